// Round 6
// baseline (145.340 us; speedup 1.0000x reference)
//
#include <hip/hip_runtime.h>

// LimitedKVWithBBPM — round 6.
// Delete the acc intermediate: each output row computes its slot sum directly
// (hit -> cache row copy; miss -> bbpm[s] + sum of bucket rows). Out writes
// stay sequential (r4 lesson). Prefetch vals AND bbpm into L3 (fused with the
// bucket-fill pass) so compute's random 512B reads run at L3 rate (~9 TB/s,
// r3 gather) instead of random-HBM (~1 TB/s).

typedef float f32x4 __attribute__((ext_vector_type(4)));
typedef int   i32x4 __attribute__((ext_vector_type(4)));

constexpr int DIM    = 128;
constexpr int MEM    = 131072;   // 2^17 -> mask
constexpr int KCACHE = 8192;
constexpr int CAP    = 8;        // token bucket capacity (mean load 2)

__device__ __forceinline__ f32x4 ldrow(const float* __restrict__ p, int q) {
    return *reinterpret_cast<const f32x4*>(p + q * 4);
}
__device__ __forceinline__ void nt_strow(float* __restrict__ p, int q, f32x4 v) {
    __builtin_nontemporal_store(v, reinterpret_cast<f32x4*>(p) + q);
}

// pos_table[positions[n-K+j]] = j
__global__ void build_pos_kernel(const int* __restrict__ positions,
                                 int* __restrict__ pos_table, int n, int K) {
    int j = blockIdx.x * 256 + threadIdx.x;
    if (j >= K) return;
    int p = positions[n - K + j];
    if (p >= 0 && p < n) pos_table[p] = j;
}

// Token bucket fill + sequential L3-warming streams of vals and bbpm.
// The atomic bucket work hides under the streaming BW.
__global__ void fill_prefetch_kernel(const int* __restrict__ keys,
                                     int* __restrict__ cnt, int* __restrict__ bucket,
                                     int* __restrict__ ovf_cnt, int* __restrict__ ovf,
                                     const f32x4* __restrict__ vals4,
                                     const f32x4* __restrict__ bbpm4,
                                     int n, int nv4, int nb4) {
    int tid = blockIdx.x * 256 + threadIdx.x;
    int nth = gridDim.x * 256;
    if (tid < n) {
        int slot = ((unsigned)keys[tid]) & (MEM - 1);
        int pos = atomicAdd(&cnt[slot], 1);
        if (pos < CAP) bucket[slot * CAP + pos] = tid;
        else { int k = atomicAdd(ovf_cnt, 1); ovf[k] = tid; }
    }
    float s = 0.f;
    for (int t = tid; t < nv4; t += nth) {
        f32x4 v = vals4[t];
        s += v.x + v.y + v.z + v.w;
    }
    for (int t = tid; t < nb4; t += nth) {
        f32x4 v = bbpm4[t];
        s += v.x + v.y + v.z + v.w;
    }
    asm volatile("" :: "v"(s));   // keep streams live (rule #17)
}

// Each 32-lane group computes 2 output rows end-to-end.
// hit  : out[r] = vals[base+idx]         (m_bbpm=0, first val row = cache row)
// miss : out[r] = bbpm[s] + sum bucket rows
// All 6 primary row loads (2 bbpm + 4 vals) issued in parallel, masked adds.
__global__ void compute_kernel(const float* __restrict__ vals,
                               const float* __restrict__ bbpm,
                               const int* __restrict__ keys,
                               const int* __restrict__ cnt,
                               const int* __restrict__ bucket,
                               const int* __restrict__ ovf_cnt,
                               const int* __restrict__ ovf,
                               const int* __restrict__ qkeys,
                               const int* __restrict__ qpos,
                               const int* __restrict__ pos_table,
                               float* __restrict__ out, int n, int base) {
    int g = threadIdx.x >> 5;
    int q = threadIdx.x & 31;
    int r0 = blockIdx.x * 16 + g;
    int r1 = r0 + 8;
    bool k0 = r0 < n, k1 = r1 < n;

    int qp0 = k0 ? qpos[r0] : -1;
    int qp1 = k1 ? qpos[r1] : -1;
    int qk0 = k0 ? qkeys[r0] : 0;
    int qk1 = k1 ? qkeys[r1] : 0;
    int i0 = (qp0 >= 0 && qp0 < n) ? pos_table[qp0] : -1;
    int i1 = (qp1 >= 0 && qp1 < n) ? pos_table[qp1] : -1;
    bool h0 = i0 >= 0, h1 = i1 >= 0;
    int s0 = ((unsigned)qk0) & (MEM - 1);
    int s1 = ((unsigned)qk1) & (MEM - 1);

    bool miss0 = k0 && !h0, miss1 = k1 && !h1;
    int c0 = miss0 ? cnt[s0] : 0;
    int c1 = miss1 ? cnt[s1] : 0;
    i32x4 b0 = *reinterpret_cast<const i32x4*>(bucket + s0 * CAP);
    i32x4 b1 = *reinterpret_cast<const i32x4*>(bucket + s1 * CAP);

    // first val row: hit -> cache row, miss -> bucket[0] (predicated to 0)
    int   vr00 = h0 ? (base + i0) : (c0 > 0 ? b0.x : 0);
    int   vr10 = h1 ? (base + i1) : (c1 > 0 ? b1.x : 0);
    float m00  = (h0 || c0 > 0) ? 1.f : 0.f;
    float m10  = (h1 || c1 > 0) ? 1.f : 0.f;
    int   vr01 = (miss0 && c0 > 1) ? b0.y : 0;
    int   vr11 = (miss1 && c1 > 1) ? b1.y : 0;
    float m01  = (miss0 && c0 > 1) ? 1.f : 0.f;
    float m11  = (miss1 && c1 > 1) ? 1.f : 0.f;
    float mb0  = miss0 ? 1.f : 0.f;
    float mb1  = miss1 ? 1.f : 0.f;
    int   bb0  = miss0 ? s0 : 0;
    int   bb1  = miss1 ? s1 : 0;

    f32x4 A0  = ldrow(bbpm + (size_t)bb0  * DIM, q);
    f32x4 A1  = ldrow(bbpm + (size_t)bb1  * DIM, q);
    f32x4 V00 = ldrow(vals + (size_t)vr00 * DIM, q);
    f32x4 V01 = ldrow(vals + (size_t)vr01 * DIM, q);
    f32x4 V10 = ldrow(vals + (size_t)vr10 * DIM, q);
    f32x4 V11 = ldrow(vals + (size_t)vr11 * DIM, q);

    f32x4 a0 = mb0 * A0 + m00 * V00 + m01 * V01;
    f32x4 a1 = mb1 * A1 + m10 * V10 + m11 * V11;

    if (miss0 && c0 > 2) {                       // P ~ 0.32
        a0 += ldrow(vals + (size_t)b0.z * DIM, q);
        if (c0 > 3) {
            a0 += ldrow(vals + (size_t)b0.w * DIM, q);
            int cc = c0 < CAP ? c0 : CAP;
            for (int j = 4; j < cc; ++j)
                a0 += ldrow(vals + (size_t)bucket[s0 * CAP + j] * DIM, q);
        }
        if (c0 > CAP) {                          // pathological keys only
            int L = *ovf_cnt;
            for (int j = 0; j < L; ++j) {
                int i = ovf[j];
                if ((((unsigned)keys[i]) & (MEM - 1)) == (unsigned)s0)
                    a0 += ldrow(vals + (size_t)i * DIM, q);
            }
        }
    }
    if (miss1 && c1 > 2) {
        a1 += ldrow(vals + (size_t)b1.z * DIM, q);
        if (c1 > 3) {
            a1 += ldrow(vals + (size_t)b1.w * DIM, q);
            int cc = c1 < CAP ? c1 : CAP;
            for (int j = 4; j < cc; ++j)
                a1 += ldrow(vals + (size_t)bucket[s1 * CAP + j] * DIM, q);
        }
        if (c1 > CAP) {
            int L = *ovf_cnt;
            for (int j = 0; j < L; ++j) {
                int i = ovf[j];
                if ((((unsigned)keys[i]) & (MEM - 1)) == (unsigned)s1)
                    a1 += ldrow(vals + (size_t)i * DIM, q);
            }
        }
    }

    if (k0) nt_strow(out + (size_t)r0 * DIM, q, a0);
    if (k1) nt_strow(out + (size_t)r1 * DIM, q, a1);
}

extern "C" void kernel_launch(void* const* d_in, const int* in_sizes, int n_in,
                              void* d_out, int out_size, void* d_ws, size_t ws_size,
                              hipStream_t stream) {
    const int*   keys      = (const int*)d_in[0];
    const float* vals      = (const float*)d_in[1];
    const int*   positions = (const int*)d_in[2];
    const int*   qkeys     = (const int*)d_in[3];
    const int*   qpos      = (const int*)d_in[4];
    const float* bbpm      = (const float*)d_in[5];
    float* out = (float*)d_out;

    const int n = in_sizes[0];                  // B*T tokens

    char* ws = (char*)d_ws;
    int* cnt       = (int*)ws;                  // MEM
    int* ctrs      = cnt + MEM;                 // 64 ([0]=ovf_cnt)
    int* pos_table = ctrs + 64;                 // n
    int* bucket    = pos_table + n;             // MEM*CAP (4 MiB)
    int* ovf       = bucket + MEM * CAP;        // n

    hipMemsetAsync(cnt, 0, (size_t)(MEM + 64) * 4, stream);
    hipMemsetAsync(pos_table, 0xFF, (size_t)n * 4, stream);

    build_pos_kernel<<<(KCACHE + 255) / 256, 256, 0, stream>>>(positions, pos_table,
                                                               n, KCACHE);
    fill_prefetch_kernel<<<(n + 255) / 256, 256, 0, stream>>>(
        keys, cnt, bucket, &ctrs[0], ovf,
        (const f32x4*)vals, (const f32x4*)bbpm,
        n, n * (DIM / 4), MEM * (DIM / 4));
    compute_kernel<<<(n + 15) / 16, 256, 0, stream>>>(
        vals, bbpm, keys, cnt, bucket, &ctrs[0], ovf,
        qkeys, qpos, pos_table, out, n, n - KCACHE);
}

// Round 7
// 129.815 us; speedup vs baseline: 1.1196x; 1.1196x over previous
//
#include <hip/hip_runtime.h>

// LimitedKVWithBBPM — round 7.
// r6 lesson: acc-dedup is worth its 64MB round-trip (acc stays L3-hot for
// gather; dup val reads cost 230MB HBM fetch). r5 lesson: standalone prefetch
// works but its 21us is serialized behind a kernel boundary. This round:
// r5 structure with the vals L3-warming stream FUSED into reduce (phase A:
// sequential 32-row chunk per block; phase B: 16 slots). Each val line crosses
// HBM once regardless of whether stream or random touches it first.

typedef float f32x4 __attribute__((ext_vector_type(4)));
typedef int   i32x4 __attribute__((ext_vector_type(4)));

constexpr int DIM    = 128;
constexpr int MEM    = 131072;   // 2^17 -> mask
constexpr int KCACHE = 8192;
constexpr int CAP    = 8;        // token bucket capacity (mean load 2)

__device__ __forceinline__ f32x4 ldrow(const float* __restrict__ p, int q) {
    return *reinterpret_cast<const f32x4*>(p + q * 4);
}
__device__ __forceinline__ f32x4 nt_ldrow(const float* __restrict__ p, int q) {
    return __builtin_nontemporal_load(reinterpret_cast<const f32x4*>(p) + q);
}
__device__ __forceinline__ void nt_strow(float* __restrict__ p, int q, f32x4 v) {
    __builtin_nontemporal_store(v, reinterpret_cast<f32x4*>(p) + q);
}

// One thread per token: claim a bucket position in its slot.
__global__ void fill_kernel(const int* __restrict__ keys,
                            int* __restrict__ cnt, int* __restrict__ bucket,
                            int* __restrict__ ovf_cnt, int* __restrict__ ovf, int n) {
    int i = blockIdx.x * 256 + threadIdx.x;
    if (i >= n) return;
    int slot = ((unsigned)keys[i]) & (MEM - 1);
    int pos = atomicAdd(&cnt[slot], 1);
    if (pos < CAP) bucket[slot * CAP + pos] = i;
    else { int k = atomicAdd(ovf_cnt, 1); ovf[k] = i; }
}

// pos_table[positions[n-K+j]] = j
__global__ void build_pos_kernel(const int* __restrict__ positions,
                                 int* __restrict__ pos_table, int n, int K) {
    int j = blockIdx.x * 256 + threadIdx.x;
    if (j >= K) return;
    int p = positions[n - K + j];
    if (p >= 0 && p < n) pos_table[p] = j;
}

// Mark slots that at least one missing query needs (benign racy store of 1).
__global__ void qfill_kernel(const int* __restrict__ qkeys,
                             const int* __restrict__ qpos,
                             const int* __restrict__ pos_table,
                             int* __restrict__ qflag, int n) {
    int r = blockIdx.x * 256 + threadIdx.x;
    if (r >= n) return;
    int qp = qpos[r];
    int idx = (qp >= 0 && qp < n) ? pos_table[qp] : -1;
    if (idx < 0) qflag[((unsigned)qkeys[r]) & (MEM - 1)] = 1;
}

// Phase A: sequentially stream this block's vals chunk (populates L3 with
// DRAM-page-friendly fetches). Phase B: dedup slot sums (2 slots per 32-lane
// group, 16 per block), random reads now mostly L3 hits. No barrier between
// phases: overlap across resident blocks is the point.
__global__ void reduce_kernel(const float* __restrict__ vals,
                              const float* __restrict__ bbpm,
                              const int* __restrict__ cnt,
                              const int* __restrict__ qflag,
                              const int* __restrict__ bucket,
                              float* __restrict__ acc,
                              const f32x4* __restrict__ vals4, int nv4) {
    // ---- phase A: stream ----
    {
        int chunk = (nv4 + gridDim.x - 1) / gridDim.x;     // 1024 for 8192 blocks
        int beg = blockIdx.x * chunk;
        int end = beg + chunk; if (end > nv4) end = nv4;
        float s = 0.f;
        for (int t = beg + (int)threadIdx.x; t < end; t += 256) {
            f32x4 v = vals4[t];
            s += v.x + v.y + v.z + v.w;
        }
        asm volatile("" :: "v"(s));     // keep stream live (rule #17)
    }

    // ---- phase B: dedup slot sums ----
    int g = threadIdx.x >> 5;
    int q = threadIdx.x & 31;
    int s0 = blockIdx.x * 16 + g;
    int s1 = s0 + 8;

    int f0 = qflag[s0], f1 = qflag[s1];
    if ((f0 | f1) == 0) return;          // group-uniform: no query needs these

    int c0 = f0 ? cnt[s0] : 0; if (c0 > CAP) c0 = CAP;
    int c1 = f1 ? cnt[s1] : 0; if (c1 > CAP) c1 = CAP;
    i32x4 b0 = *reinterpret_cast<const i32x4*>(bucket + s0 * CAP);
    i32x4 b1 = *reinterpret_cast<const i32x4*>(bucket + s1 * CAP);

    int r00 = c0 > 0 ? b0.x : 0, r01 = c0 > 1 ? b0.y : 0;
    int r10 = c1 > 0 ? b1.x : 0, r11 = c1 > 1 ? b1.y : 0;
    float m00 = c0 > 0 ? 1.f : 0.f, m01 = c0 > 1 ? 1.f : 0.f;
    float m10 = c1 > 0 ? 1.f : 0.f, m11 = c1 > 1 ? 1.f : 0.f;

    // bbpm is read-once and slot-ordered: NT avoids evicting vals/acc in L3.
    const float* bb0 = bbpm + (f0 ? (size_t)s0 * DIM : 0);
    const float* bb1 = bbpm + (f1 ? (size_t)s1 * DIM : 0);
    f32x4 A0  = nt_ldrow(bb0, q);
    f32x4 A1  = nt_ldrow(bb1, q);
    f32x4 V00 = ldrow(vals + (size_t)r00 * DIM, q);
    f32x4 V01 = ldrow(vals + (size_t)r01 * DIM, q);
    f32x4 V10 = ldrow(vals + (size_t)r10 * DIM, q);
    f32x4 V11 = ldrow(vals + (size_t)r11 * DIM, q);

    f32x4 a0 = A0 + m00 * V00 + m01 * V01;
    f32x4 a1 = A1 + m10 * V10 + m11 * V11;

    if (c0 > 2) {
        a0 += ldrow(vals + (size_t)b0.z * DIM, q);
        if (c0 > 3) {
            a0 += ldrow(vals + (size_t)b0.w * DIM, q);
            for (int j = 4; j < c0; ++j)
                a0 += ldrow(vals + (size_t)bucket[s0 * CAP + j] * DIM, q);
        }
    }
    if (c1 > 2) {
        a1 += ldrow(vals + (size_t)b1.z * DIM, q);
        if (c1 > 3) {
            a1 += ldrow(vals + (size_t)b1.w * DIM, q);
            for (int j = 4; j < c1; ++j)
                a1 += ldrow(vals + (size_t)bucket[s1 * CAP + j] * DIM, q);
        }
    }

    if (f0) *reinterpret_cast<f32x4*>(acc + (size_t)s0 * DIM + q * 4) = a0;
    if (f1) *reinterpret_cast<f32x4*>(acc + (size_t)s1 * DIM + q * 4) = a1;
}

// Rare path: tokens beyond CAP get atomic-added (expected ~0 for these keys).
__global__ void overflow_kernel(const float* __restrict__ vals,
                                const int* __restrict__ keys,
                                const int* __restrict__ ovf_cnt,
                                const int* __restrict__ ovf,
                                float* __restrict__ acc) {
    int total = *ovf_cnt;
    int tid = blockIdx.x * 256 + threadIdx.x, stride = gridDim.x * 256;
    for (int w = tid; w < total * 32; w += stride) {
        int e = w >> 5, q = w & 31;
        int i = ovf[e];
        int slot = ((unsigned)keys[i]) & (MEM - 1);
        f32x4 v = ldrow(vals + (size_t)i * DIM, q);
        float* dst = acc + (size_t)slot * DIM + q * 4;
        atomicAdd(dst + 0, v.x);
        atomicAdd(dst + 1, v.y);
        atomicAdd(dst + 2, v.z);
        atomicAdd(dst + 3, v.w);
    }
}

// 4 output rows per 32-lane group; sequential NT out writes.
__global__ void gather_kernel(const float* __restrict__ vals,
                              const float* __restrict__ acc,
                              const int* __restrict__ qkeys,
                              const int* __restrict__ qpos,
                              const int* __restrict__ pos_table,
                              float* __restrict__ out, int n, int base) {
    int g = threadIdx.x >> 5;
    int q = threadIdx.x & 31;
    int r0 = blockIdx.x * 32 + g;
    int r1 = r0 + 8, r2 = r0 + 16, r3 = r0 + 24;

    bool k0 = r0 < n, k1 = r1 < n, k2 = r2 < n, k3 = r3 < n;
    int qp0 = k0 ? qpos[r0] : -1, qp1 = k1 ? qpos[r1] : -1;
    int qp2 = k2 ? qpos[r2] : -1, qp3 = k3 ? qpos[r3] : -1;
    int qk0 = k0 ? qkeys[r0] : 0, qk1 = k1 ? qkeys[r1] : 0;
    int qk2 = k2 ? qkeys[r2] : 0, qk3 = k3 ? qkeys[r3] : 0;

    int i0 = (qp0 >= 0 && qp0 < n) ? pos_table[qp0] : -1;
    int i1 = (qp1 >= 0 && qp1 < n) ? pos_table[qp1] : -1;
    int i2 = (qp2 >= 0 && qp2 < n) ? pos_table[qp2] : -1;
    int i3 = (qp3 >= 0 && qp3 < n) ? pos_table[qp3] : -1;

    const float* s0 = (i0 >= 0) ? vals + (size_t)(base + i0) * DIM
                                : acc + (size_t)(((unsigned)qk0) & (MEM - 1)) * DIM;
    const float* s1 = (i1 >= 0) ? vals + (size_t)(base + i1) * DIM
                                : acc + (size_t)(((unsigned)qk1) & (MEM - 1)) * DIM;
    const float* s2 = (i2 >= 0) ? vals + (size_t)(base + i2) * DIM
                                : acc + (size_t)(((unsigned)qk2) & (MEM - 1)) * DIM;
    const float* s3 = (i3 >= 0) ? vals + (size_t)(base + i3) * DIM
                                : acc + (size_t)(((unsigned)qk3) & (MEM - 1)) * DIM;

    f32x4 v0 = ldrow(s0, q);
    f32x4 v1 = ldrow(s1, q);
    f32x4 v2 = ldrow(s2, q);
    f32x4 v3 = ldrow(s3, q);

    if (k0) nt_strow(out + (size_t)r0 * DIM, q, v0);
    if (k1) nt_strow(out + (size_t)r1 * DIM, q, v1);
    if (k2) nt_strow(out + (size_t)r2 * DIM, q, v2);
    if (k3) nt_strow(out + (size_t)r3 * DIM, q, v3);
}

extern "C" void kernel_launch(void* const* d_in, const int* in_sizes, int n_in,
                              void* d_out, int out_size, void* d_ws, size_t ws_size,
                              hipStream_t stream) {
    const int*   keys      = (const int*)d_in[0];
    const float* vals      = (const float*)d_in[1];
    const int*   positions = (const int*)d_in[2];
    const int*   qkeys     = (const int*)d_in[3];
    const int*   qpos      = (const int*)d_in[4];
    const float* bbpm      = (const float*)d_in[5];
    float* out = (float*)d_out;

    const int n = in_sizes[0];                  // B*T tokens

    char* ws = (char*)d_ws;
    int*   cnt       = (int*)ws;                       // MEM
    int*   qflag     = cnt + MEM;                      // MEM
    int*   ctrs      = qflag + MEM;                    // 64  ([0]=ovf_cnt)
    int*   pos_table = ctrs + 64;                      // n
    int*   bucket    = pos_table + n;                  // MEM*CAP (4 MiB)
    int*   ovf       = bucket + MEM * CAP;             // n
    float* acc       = (float*)(ovf + n);              // MEM*DIM (64 MiB)

    hipMemsetAsync(cnt, 0, (size_t)(2 * MEM + 64) * 4, stream);
    hipMemsetAsync(pos_table, 0xFF, (size_t)n * 4, stream);

    fill_kernel<<<(n + 255) / 256, 256, 0, stream>>>(keys, cnt, bucket, &ctrs[0], ovf, n);
    build_pos_kernel<<<(KCACHE + 255) / 256, 256, 0, stream>>>(positions, pos_table, n, KCACHE);
    qfill_kernel<<<(n + 255) / 256, 256, 0, stream>>>(qkeys, qpos, pos_table, qflag, n);
    reduce_kernel<<<MEM / 16, 256, 0, stream>>>(vals, bbpm, cnt, qflag, bucket, acc,
                                                (const f32x4*)vals, n * (DIM / 4));
    overflow_kernel<<<64, 256, 0, stream>>>(vals, keys, &ctrs[0], ovf, acc);
    gather_kernel<<<(n + 31) / 32, 256, 0, stream>>>(vals, acc, qkeys, qpos, pos_table,
                                                     out, n, n - KCACHE);
}

// Round 8
// 128.273 us; speedup vs baseline: 1.1331x; 1.0120x over previous
//
#include <hip/hip_runtime.h>

// LimitedKVWithBBPM — round 8.
// r7 lesson: the limiter is total cache-LINE count through the per-CU L2-miss
// queue (~37K lines/us random vs 78K mixed); fusing the stream into reduce
// gained ~0 because both share the queue. This round cuts the SERIAL front-end
// (fill -> qfill were 18us of launches before reduce): build_pos (2us), then
// one fused kernel doing fill + qfill + the sequential vals stream (atomics
// hide under the 21us stream). Reduce = phase B only, parallel metadata loads.

typedef float f32x4 __attribute__((ext_vector_type(4)));
typedef int   i32x4 __attribute__((ext_vector_type(4)));

constexpr int DIM    = 128;
constexpr int MEM    = 131072;   // 2^17 -> mask
constexpr int KCACHE = 8192;
constexpr int CAP    = 8;        // token bucket capacity (mean load 2)

__device__ __forceinline__ f32x4 ldrow(const float* __restrict__ p, int q) {
    return *reinterpret_cast<const f32x4*>(p + q * 4);
}
__device__ __forceinline__ f32x4 nt_ldrow(const float* __restrict__ p, int q) {
    return __builtin_nontemporal_load(reinterpret_cast<const f32x4*>(p) + q);
}
__device__ __forceinline__ void nt_strow(float* __restrict__ p, int q, f32x4 v) {
    __builtin_nontemporal_store(v, reinterpret_cast<f32x4*>(p) + q);
}

// pos_table[positions[n-K+j]] = j  (tiny; runs first)
__global__ void build_pos_kernel(const int* __restrict__ positions,
                                 int* __restrict__ pos_table, int n, int K) {
    int j = blockIdx.x * 256 + threadIdx.x;
    if (j >= K) return;
    int p = positions[n - K + j];
    if (p >= 0 && p < n) pos_table[p] = j;
}

// Fused: token bucket fill + query hit-test/qflag + sequential vals stream.
// All three are independent given pos_table; the scatter/atomic latency hides
// under the streaming BW. Grid = n/256 blocks; each block streams a contiguous
// 128KB chunk of vals (page-friendly, coalesced).
__global__ void front_kernel(const int* __restrict__ keys,
                             int* __restrict__ cnt, int* __restrict__ bucket,
                             int* __restrict__ ovf_cnt, int* __restrict__ ovf,
                             const int* __restrict__ qkeys,
                             const int* __restrict__ qpos,
                             const int* __restrict__ pos_table,
                             int* __restrict__ qflag,
                             const f32x4* __restrict__ vals4,
                             int n, int nv4) {
    int tid = blockIdx.x * 256 + threadIdx.x;

    // --- fill: claim bucket position for token tid ---
    if (tid < n) {
        int slot = ((unsigned)keys[tid]) & (MEM - 1);
        int pos = atomicAdd(&cnt[slot], 1);
        if (pos < CAP) bucket[slot * CAP + pos] = tid;
        else { int k = atomicAdd(ovf_cnt, 1); ovf[k] = tid; }
    }
    // --- qfill: mark slot needed if query tid misses the cache ---
    if (tid < n) {
        int qp = qpos[tid];
        int idx = (qp >= 0 && qp < n) ? pos_table[qp] : -1;
        if (idx < 0) qflag[((unsigned)qkeys[tid]) & (MEM - 1)] = 1;
    }
    // --- stream: contiguous per-block chunk of vals -> L3 ---
    int chunk = (nv4 + gridDim.x - 1) / gridDim.x;
    int beg = blockIdx.x * chunk;
    int end = beg + chunk; if (end > nv4) end = nv4;
    float s = 0.f;
    for (int t = beg + (int)threadIdx.x; t < end; t += 256) {
        f32x4 v = vals4[t];
        s += v.x + v.y + v.z + v.w;
    }
    asm volatile("" :: "v"(s));   // keep stream live (rule #17)
}

// Dedup slot sums: 2 slots per 32-lane group, 16 per block. qflag/cnt/bucket
// loaded in parallel (no serial gating); random val reads are L3 hits after
// the front stream; bbpm reads are sequential-in-slot-order NT; acc write
// sequential (stays L3-hot for gather).
__global__ void __launch_bounds__(256, 8)
reduce_kernel(const float* __restrict__ vals,
              const float* __restrict__ bbpm,
              const int* __restrict__ cnt,
              const int* __restrict__ qflag,
              const int* __restrict__ bucket,
              float* __restrict__ acc) {
    int g = threadIdx.x >> 5;
    int q = threadIdx.x & 31;
    int s0 = blockIdx.x * 16 + g;
    int s1 = s0 + 8;

    // parallel metadata loads
    int f0 = qflag[s0], f1 = qflag[s1];
    int n0 = cnt[s0],   n1 = cnt[s1];
    i32x4 b0 = *reinterpret_cast<const i32x4*>(bucket + s0 * CAP);
    i32x4 b1 = *reinterpret_cast<const i32x4*>(bucket + s1 * CAP);
    if ((f0 | f1) == 0) return;          // group-uniform early exit

    int c0 = f0 ? (n0 > CAP ? CAP : n0) : 0;
    int c1 = f1 ? (n1 > CAP ? CAP : n1) : 0;

    int r00 = c0 > 0 ? b0.x : 0, r01 = c0 > 1 ? b0.y : 0;
    int r10 = c1 > 0 ? b1.x : 0, r11 = c1 > 1 ? b1.y : 0;
    float m00 = c0 > 0 ? 1.f : 0.f, m01 = c0 > 1 ? 1.f : 0.f;
    float m10 = c1 > 0 ? 1.f : 0.f, m11 = c1 > 1 ? 1.f : 0.f;

    const float* bb0 = bbpm + (f0 ? (size_t)s0 * DIM : 0);
    const float* bb1 = bbpm + (f1 ? (size_t)s1 * DIM : 0);
    f32x4 A0  = nt_ldrow(bb0, q);
    f32x4 A1  = nt_ldrow(bb1, q);
    f32x4 V00 = ldrow(vals + (size_t)r00 * DIM, q);
    f32x4 V01 = ldrow(vals + (size_t)r01 * DIM, q);
    f32x4 V10 = ldrow(vals + (size_t)r10 * DIM, q);
    f32x4 V11 = ldrow(vals + (size_t)r11 * DIM, q);

    f32x4 a0 = A0 + m00 * V00 + m01 * V01;
    f32x4 a1 = A1 + m10 * V10 + m11 * V11;

    if (c0 > 2) {
        a0 += ldrow(vals + (size_t)b0.z * DIM, q);
        if (c0 > 3) {
            a0 += ldrow(vals + (size_t)b0.w * DIM, q);
            for (int j = 4; j < c0; ++j)
                a0 += ldrow(vals + (size_t)bucket[s0 * CAP + j] * DIM, q);
        }
    }
    if (c1 > 2) {
        a1 += ldrow(vals + (size_t)b1.z * DIM, q);
        if (c1 > 3) {
            a1 += ldrow(vals + (size_t)b1.w * DIM, q);
            for (int j = 4; j < c1; ++j)
                a1 += ldrow(vals + (size_t)bucket[s1 * CAP + j] * DIM, q);
        }
    }

    if (f0) *reinterpret_cast<f32x4*>(acc + (size_t)s0 * DIM + q * 4) = a0;
    if (f1) *reinterpret_cast<f32x4*>(acc + (size_t)s1 * DIM + q * 4) = a1;
}

// Rare path: tokens beyond CAP get atomic-added (expected ~0 for these keys).
__global__ void overflow_kernel(const float* __restrict__ vals,
                                const int* __restrict__ keys,
                                const int* __restrict__ ovf_cnt,
                                const int* __restrict__ ovf,
                                float* __restrict__ acc) {
    int total = *ovf_cnt;
    int tid = blockIdx.x * 256 + threadIdx.x, stride = gridDim.x * 256;
    for (int w = tid; w < total * 32; w += stride) {
        int e = w >> 5, q = w & 31;
        int i = ovf[e];
        int slot = ((unsigned)keys[i]) & (MEM - 1);
        f32x4 v = ldrow(vals + (size_t)i * DIM, q);
        float* dst = acc + (size_t)slot * DIM + q * 4;
        atomicAdd(dst + 0, v.x);
        atomicAdd(dst + 1, v.y);
        atomicAdd(dst + 2, v.z);
        atomicAdd(dst + 3, v.w);
    }
}

// 4 output rows per 32-lane group; random reads from L3-hot acc/vals,
// sequential NT out writes.
__global__ void gather_kernel(const float* __restrict__ vals,
                              const float* __restrict__ acc,
                              const int* __restrict__ qkeys,
                              const int* __restrict__ qpos,
                              const int* __restrict__ pos_table,
                              float* __restrict__ out, int n, int base) {
    int g = threadIdx.x >> 5;
    int q = threadIdx.x & 31;
    int r0 = blockIdx.x * 32 + g;
    int r1 = r0 + 8, r2 = r0 + 16, r3 = r0 + 24;

    bool k0 = r0 < n, k1 = r1 < n, k2 = r2 < n, k3 = r3 < n;
    int qp0 = k0 ? qpos[r0] : -1, qp1 = k1 ? qpos[r1] : -1;
    int qp2 = k2 ? qpos[r2] : -1, qp3 = k3 ? qpos[r3] : -1;
    int qk0 = k0 ? qkeys[r0] : 0, qk1 = k1 ? qkeys[r1] : 0;
    int qk2 = k2 ? qkeys[r2] : 0, qk3 = k3 ? qkeys[r3] : 0;

    int i0 = (qp0 >= 0 && qp0 < n) ? pos_table[qp0] : -1;
    int i1 = (qp1 >= 0 && qp1 < n) ? pos_table[qp1] : -1;
    int i2 = (qp2 >= 0 && qp2 < n) ? pos_table[qp2] : -1;
    int i3 = (qp3 >= 0 && qp3 < n) ? pos_table[qp3] : -1;

    const float* s0 = (i0 >= 0) ? vals + (size_t)(base + i0) * DIM
                                : acc + (size_t)(((unsigned)qk0) & (MEM - 1)) * DIM;
    const float* s1 = (i1 >= 0) ? vals + (size_t)(base + i1) * DIM
                                : acc + (size_t)(((unsigned)qk1) & (MEM - 1)) * DIM;
    const float* s2 = (i2 >= 0) ? vals + (size_t)(base + i2) * DIM
                                : acc + (size_t)(((unsigned)qk2) & (MEM - 1)) * DIM;
    const float* s3 = (i3 >= 0) ? vals + (size_t)(base + i3) * DIM
                                : acc + (size_t)(((unsigned)qk3) & (MEM - 1)) * DIM;

    f32x4 v0 = ldrow(s0, q);
    f32x4 v1 = ldrow(s1, q);
    f32x4 v2 = ldrow(s2, q);
    f32x4 v3 = ldrow(s3, q);

    if (k0) nt_strow(out + (size_t)r0 * DIM, q, v0);
    if (k1) nt_strow(out + (size_t)r1 * DIM, q, v1);
    if (k2) nt_strow(out + (size_t)r2 * DIM, q, v2);
    if (k3) nt_strow(out + (size_t)r3 * DIM, q, v3);
}

extern "C" void kernel_launch(void* const* d_in, const int* in_sizes, int n_in,
                              void* d_out, int out_size, void* d_ws, size_t ws_size,
                              hipStream_t stream) {
    const int*   keys      = (const int*)d_in[0];
    const float* vals      = (const float*)d_in[1];
    const int*   positions = (const int*)d_in[2];
    const int*   qkeys     = (const int*)d_in[3];
    const int*   qpos      = (const int*)d_in[4];
    const float* bbpm      = (const float*)d_in[5];
    float* out = (float*)d_out;

    const int n = in_sizes[0];                  // B*T tokens

    char* ws = (char*)d_ws;
    int*   cnt       = (int*)ws;                       // MEM
    int*   qflag     = cnt + MEM;                      // MEM
    int*   ctrs      = qflag + MEM;                    // 64  ([0]=ovf_cnt)
    int*   pos_table = ctrs + 64;                      // n
    int*   bucket    = pos_table + n;                  // MEM*CAP (4 MiB)
    int*   ovf       = bucket + MEM * CAP;             // n
    float* acc       = (float*)(ovf + n);              // MEM*DIM (64 MiB)

    hipMemsetAsync(cnt, 0, (size_t)(2 * MEM + 64) * 4, stream);
    hipMemsetAsync(pos_table, 0xFF, (size_t)n * 4, stream);

    build_pos_kernel<<<(KCACHE + 255) / 256, 256, 0, stream>>>(positions, pos_table,
                                                               n, KCACHE);
    front_kernel<<<(n + 255) / 256, 256, 0, stream>>>(
        keys, cnt, bucket, &ctrs[0], ovf,
        qkeys, qpos, pos_table, qflag,
        (const f32x4*)vals, n, n * (DIM / 4));
    reduce_kernel<<<MEM / 16, 256, 0, stream>>>(vals, bbpm, cnt, qflag, bucket, acc);
    overflow_kernel<<<64, 256, 0, stream>>>(vals, keys, &ctrs[0], ovf, acc);
    gather_kernel<<<(n + 31) / 32, 256, 0, stream>>>(vals, acc, qkeys, qpos, pos_table,
                                                     out, n, n - KCACHE);
}

// Round 9
// 117.510 us; speedup vs baseline: 1.2368x; 1.0916x over previous
//
#include <hip/hip_runtime.h>

// LimitedKVWithBBPM — round 9.
// r8 lesson: stream+random-reduce is line-count bound (~80us invariant under
// rearrangement). Cut LINES and DISPATCHES: (1) bf16 acc — halves reduce's
// write and gather's random acc reads (threshold 0.259 tolerates one bf16
// round; sums stay fp32 in-register); (2) 7 -> 4 dispatches: one memset
// (pos_table 0=empty/j+1), build_pos fused into front (qflag marks ALL query
// slots; +0.3% reduce work), overflow inlined into reduce (also avoids bf16
// atomics); (3) r8 structure otherwise unchanged.

typedef float f32x4 __attribute__((ext_vector_type(4)));
typedef int   i32x4 __attribute__((ext_vector_type(4)));
typedef unsigned short u16x4 __attribute__((ext_vector_type(4)));

constexpr int DIM    = 128;
constexpr int MEM    = 131072;   // 2^17 -> mask
constexpr int KCACHE = 8192;
constexpr int CAP    = 8;        // token bucket capacity (mean load 2)

__device__ __forceinline__ f32x4 ldrow(const float* __restrict__ p, int q) {
    return *reinterpret_cast<const f32x4*>(p + q * 4);
}
__device__ __forceinline__ f32x4 nt_ldrow(const float* __restrict__ p, int q) {
    return __builtin_nontemporal_load(reinterpret_cast<const f32x4*>(p) + q);
}
__device__ __forceinline__ void nt_strow(float* __restrict__ p, int q, f32x4 v) {
    __builtin_nontemporal_store(v, reinterpret_cast<f32x4*>(p) + q);
}
__device__ __forceinline__ unsigned short f2bf(float x) {   // RNE round
    union { float f; unsigned u; } c; c.f = x;
    unsigned r = c.u + 0x7FFF + ((c.u >> 16) & 1);
    return (unsigned short)(r >> 16);
}
__device__ __forceinline__ u16x4 pack_bf(f32x4 v) {
    u16x4 h; h.x = f2bf(v.x); h.y = f2bf(v.y); h.z = f2bf(v.z); h.w = f2bf(v.w);
    return h;
}
__device__ __forceinline__ f32x4 unpack_bf(u16x4 h) {
    union { unsigned u; float f; } a, b, c, d;
    a.u = (unsigned)h.x << 16; b.u = (unsigned)h.y << 16;
    c.u = (unsigned)h.z << 16; d.u = (unsigned)h.w << 16;
    f32x4 v; v.x = a.f; v.y = b.f; v.z = c.f; v.w = d.f;
    return v;
}

// Fused front end: token bucket fill + qflag (ALL query slots) + pos_table
// build + sequential vals stream. All independent; scatter/atomic latency
// hides under the 134 MB stream.
__global__ void front_kernel(const int* __restrict__ keys,
                             int* __restrict__ cnt, int* __restrict__ bucket,
                             int* __restrict__ ovf_cnt, int* __restrict__ ovf,
                             const int* __restrict__ qkeys,
                             int* __restrict__ qflag,
                             const int* __restrict__ positions,
                             int* __restrict__ pos_table,
                             const f32x4* __restrict__ vals4,
                             int n, int nv4) {
    int tid = blockIdx.x * 256 + threadIdx.x;

    if (tid < n) {
        int slot = ((unsigned)keys[tid]) & (MEM - 1);
        int pos = atomicAdd(&cnt[slot], 1);
        if (pos < CAP) bucket[slot * CAP + pos] = tid;
        else { int k = atomicAdd(ovf_cnt, 1); ovf[k] = tid; }
        // mark slot of EVERY query (hit or miss): no pos_table dependency
        qflag[((unsigned)qkeys[tid]) & (MEM - 1)] = 1;
    }
    if (tid < KCACHE) {
        int p = positions[n - KCACHE + tid];
        if (p >= 0 && p < n) pos_table[p] = tid + 1;   // +1: 0 = empty
    }
    // sequential per-block chunk of vals -> L3
    int chunk = (nv4 + gridDim.x - 1) / gridDim.x;
    int beg = blockIdx.x * chunk;
    int end = beg + chunk; if (end > nv4) end = nv4;
    float s = 0.f;
    for (int t = beg + (int)threadIdx.x; t < end; t += 256) {
        f32x4 v = vals4[t];
        s += v.x + v.y + v.z + v.w;
    }
    asm volatile("" :: "v"(s));   // keep stream live (rule #17)
}

// Dedup slot sums -> bf16 acc. 2 slots per 32-lane group, 16 per block.
// fp32 accumulation in-register; one bf16 round on store. Overflow slots
// (c > CAP, ~tens chip-wide) handled inline by scanning the tiny ovf list.
__global__ void __launch_bounds__(256, 8)
reduce_kernel(const float* __restrict__ vals,
              const float* __restrict__ bbpm,
              const int* __restrict__ keys,
              const int* __restrict__ cnt,
              const int* __restrict__ qflag,
              const int* __restrict__ bucket,
              const int* __restrict__ ovf_cnt,
              const int* __restrict__ ovf,
              unsigned short* __restrict__ acc16) {
    int g = threadIdx.x >> 5;
    int q = threadIdx.x & 31;
    int s0 = blockIdx.x * 16 + g;
    int s1 = s0 + 8;

    int f0 = qflag[s0], f1 = qflag[s1];
    int n0 = cnt[s0],   n1 = cnt[s1];
    i32x4 b0 = *reinterpret_cast<const i32x4*>(bucket + s0 * CAP);
    i32x4 b1 = *reinterpret_cast<const i32x4*>(bucket + s1 * CAP);
    if ((f0 | f1) == 0) return;

    int c0 = f0 ? (n0 > CAP ? CAP : n0) : 0;
    int c1 = f1 ? (n1 > CAP ? CAP : n1) : 0;

    int r00 = c0 > 0 ? b0.x : 0, r01 = c0 > 1 ? b0.y : 0;
    int r10 = c1 > 0 ? b1.x : 0, r11 = c1 > 1 ? b1.y : 0;
    float m00 = c0 > 0 ? 1.f : 0.f, m01 = c0 > 1 ? 1.f : 0.f;
    float m10 = c1 > 0 ? 1.f : 0.f, m11 = c1 > 1 ? 1.f : 0.f;

    const float* bb0 = bbpm + (f0 ? (size_t)s0 * DIM : 0);
    const float* bb1 = bbpm + (f1 ? (size_t)s1 * DIM : 0);
    f32x4 A0  = nt_ldrow(bb0, q);
    f32x4 A1  = nt_ldrow(bb1, q);
    f32x4 V00 = ldrow(vals + (size_t)r00 * DIM, q);
    f32x4 V01 = ldrow(vals + (size_t)r01 * DIM, q);
    f32x4 V10 = ldrow(vals + (size_t)r10 * DIM, q);
    f32x4 V11 = ldrow(vals + (size_t)r11 * DIM, q);

    f32x4 a0 = A0 + m00 * V00 + m01 * V01;
    f32x4 a1 = A1 + m10 * V10 + m11 * V11;

    if (c0 > 2) {
        a0 += ldrow(vals + (size_t)b0.z * DIM, q);
        if (c0 > 3) {
            a0 += ldrow(vals + (size_t)b0.w * DIM, q);
            for (int j = 4; j < c0; ++j)
                a0 += ldrow(vals + (size_t)bucket[s0 * CAP + j] * DIM, q);
        }
        if (f0 && n0 > CAP) {                     // pathological keys only
            int L = *ovf_cnt;
            for (int j = 0; j < L; ++j) {
                int i = ovf[j];
                if ((((unsigned)keys[i]) & (MEM - 1)) == (unsigned)s0)
                    a0 += ldrow(vals + (size_t)i * DIM, q);
            }
        }
    }
    if (c1 > 2) {
        a1 += ldrow(vals + (size_t)b1.z * DIM, q);
        if (c1 > 3) {
            a1 += ldrow(vals + (size_t)b1.w * DIM, q);
            for (int j = 4; j < c1; ++j)
                a1 += ldrow(vals + (size_t)bucket[s1 * CAP + j] * DIM, q);
        }
        if (f1 && n1 > CAP) {
            int L = *ovf_cnt;
            for (int j = 0; j < L; ++j) {
                int i = ovf[j];
                if ((((unsigned)keys[i]) & (MEM - 1)) == (unsigned)s1)
                    a1 += ldrow(vals + (size_t)i * DIM, q);
            }
        }
    }

    if (f0) *reinterpret_cast<u16x4*>(acc16 + (size_t)s0 * DIM + q * 4) = pack_bf(a0);
    if (f1) *reinterpret_cast<u16x4*>(acc16 + (size_t)s1 * DIM + q * 4) = pack_bf(a1);
}

// 4 output rows per 32-lane group. hit -> fp32 vals row; miss -> bf16 acc row
// (half the random lines of fp32 acc). Sequential NT out writes.
__global__ void gather_kernel(const float* __restrict__ vals,
                              const unsigned short* __restrict__ acc16,
                              const int* __restrict__ qkeys,
                              const int* __restrict__ qpos,
                              const int* __restrict__ pos_table,
                              float* __restrict__ out, int n, int base) {
    int g = threadIdx.x >> 5;
    int q = threadIdx.x & 31;
    int r0 = blockIdx.x * 32 + g;
    int r1 = r0 + 8, r2 = r0 + 16, r3 = r0 + 24;

    bool k0 = r0 < n, k1 = r1 < n, k2 = r2 < n, k3 = r3 < n;
    int qp0 = k0 ? qpos[r0] : -1, qp1 = k1 ? qpos[r1] : -1;
    int qp2 = k2 ? qpos[r2] : -1, qp3 = k3 ? qpos[r3] : -1;
    int qk0 = k0 ? qkeys[r0] : 0, qk1 = k1 ? qkeys[r1] : 0;
    int qk2 = k2 ? qkeys[r2] : 0, qk3 = k3 ? qkeys[r3] : 0;

    int i0 = (qp0 >= 0 && qp0 < n) ? pos_table[qp0] - 1 : -1;
    int i1 = (qp1 >= 0 && qp1 < n) ? pos_table[qp1] - 1 : -1;
    int i2 = (qp2 >= 0 && qp2 < n) ? pos_table[qp2] - 1 : -1;
    int i3 = (qp3 >= 0 && qp3 < n) ? pos_table[qp3] - 1 : -1;

    f32x4 v0, v1, v2, v3;
    if (i0 >= 0) v0 = ldrow(vals + (size_t)(base + i0) * DIM, q);
    else v0 = unpack_bf(*reinterpret_cast<const u16x4*>(
                 acc16 + (size_t)(((unsigned)qk0) & (MEM - 1)) * DIM + q * 4));
    if (i1 >= 0) v1 = ldrow(vals + (size_t)(base + i1) * DIM, q);
    else v1 = unpack_bf(*reinterpret_cast<const u16x4*>(
                 acc16 + (size_t)(((unsigned)qk1) & (MEM - 1)) * DIM + q * 4));
    if (i2 >= 0) v2 = ldrow(vals + (size_t)(base + i2) * DIM, q);
    else v2 = unpack_bf(*reinterpret_cast<const u16x4*>(
                 acc16 + (size_t)(((unsigned)qk2) & (MEM - 1)) * DIM + q * 4));
    if (i3 >= 0) v3 = ldrow(vals + (size_t)(base + i3) * DIM, q);
    else v3 = unpack_bf(*reinterpret_cast<const u16x4*>(
                 acc16 + (size_t)(((unsigned)qk3) & (MEM - 1)) * DIM + q * 4));

    if (k0) nt_strow(out + (size_t)r0 * DIM, q, v0);
    if (k1) nt_strow(out + (size_t)r1 * DIM, q, v1);
    if (k2) nt_strow(out + (size_t)r2 * DIM, q, v2);
    if (k3) nt_strow(out + (size_t)r3 * DIM, q, v3);
}

extern "C" void kernel_launch(void* const* d_in, const int* in_sizes, int n_in,
                              void* d_out, int out_size, void* d_ws, size_t ws_size,
                              hipStream_t stream) {
    const int*   keys      = (const int*)d_in[0];
    const float* vals      = (const float*)d_in[1];
    const int*   positions = (const int*)d_in[2];
    const int*   qkeys     = (const int*)d_in[3];
    const int*   qpos      = (const int*)d_in[4];
    const float* bbpm      = (const float*)d_in[5];
    float* out = (float*)d_out;

    const int n = in_sizes[0];                  // B*T tokens

    // ws layout: [cnt MEM][qflag MEM][ctrs 64][pos_table n]  <- one memset(0)
    //            [bucket MEM*CAP][ovf n][acc16 MEM*DIM u16]
    char* ws = (char*)d_ws;
    int*   cnt       = (int*)ws;
    int*   qflag     = cnt + MEM;
    int*   ctrs      = qflag + MEM;             // [0] = ovf_cnt
    int*   pos_table = ctrs + 64;
    int*   bucket    = pos_table + n;
    int*   ovf       = bucket + MEM * CAP;
    unsigned short* acc16 = (unsigned short*)(ovf + n);

    hipMemsetAsync(cnt, 0, (size_t)(2 * MEM + 64 + n) * 4, stream);

    front_kernel<<<(n + 255) / 256, 256, 0, stream>>>(
        keys, cnt, bucket, &ctrs[0], ovf, qkeys, qflag,
        positions, pos_table, (const f32x4*)vals, n, n * (DIM / 4));
    reduce_kernel<<<MEM / 16, 256, 0, stream>>>(
        vals, bbpm, keys, cnt, qflag, bucket, &ctrs[0], ovf, acc16);
    gather_kernel<<<(n + 31) / 32, 256, 0, stream>>>(
        vals, acc16, qkeys, qpos, pos_table, out, n, n - KCACHE);
}